// Round 7
// baseline (67.154 us; speedup 1.0000x reference)
//
#include <hip/hip_runtime.h>

#define LL 4096
#define THREADS 512
#define KK 8

typedef float v2f __attribute__((ext_vector_type(2)));

// XOR swizzle for 8-byte LDS elements: all FFT patterns uniform over bank pairs.
#define SW(i) ((i) ^ (((i) >> 3) & 15))
// dft8: X[k0+4*k1] sits in slot 2*k0+k1 -> slot holding X[r]:
#define PERM8(r) ((((r) & 3) << 1) | ((r) >> 2))

// HW trig, input in REVOLUTIONS: sinr(x)=sin(2*pi*x). All args are exact
// m/2^k in [0,1), so no range-reduction error.
__device__ __forceinline__ float sinr(float x) {
    float r; asm("v_sin_f32 %0, %1" : "=v"(r) : "v"(x)); return r;
}
__device__ __forceinline__ float cosr(float x) {
    float r; asm("v_cos_f32 %0, %1" : "=v"(r) : "v"(x)); return r;
}

// twiddle apply: multiply z=(zr,zi) by (c - i*s), w=(c,s)
__device__ __forceinline__ v2f cmulw(v2f z, v2f w) {
    v2f zs = __builtin_shufflevector(z, z, 1, 0);      // (zi, zr)
    v2f res = z * (v2f){w.x, w.x};
    res += zs * (v2f){w.y, -w.y};
    return res;
}
// standard complex multiply (a.x+i a.y)(b.x+i b.y)
__device__ __forceinline__ v2f cmul(v2f a, v2f b) {
    v2f as = __builtin_shufflevector(a, a, 1, 0);
    v2f res = a * (v2f){b.x, b.x};
    res += as * (v2f){-b.y, b.y};
    return res;
}

// forward 4-point DFT (w4 = -i), in place, complex-packed
__device__ __forceinline__ void dft4(v2f& a, v2f& b, v2f& c, v2f& d) {
    v2f t0 = a + c, t1 = a - c, t2 = b + d, t3 = b - d;
    a = t0 + t2; c = t0 - t2;
    v2f t3n = (v2f){t3.y, -t3.x};   // -i * t3
    b = t1 + t3n; d = t1 - t3n;
}

// forward 8-point DFT; output permuted per PERM8
__device__ __forceinline__ void dft8(v2f* v) {
    dft4(v[0], v[2], v[4], v[6]);
    dft4(v[1], v[3], v[5], v[7]);
    const float C2 = 0.70710678118654752f;
    v[3] = cmulw(v[3], (v2f){C2, C2});     // w8^1
    v[5] = (v2f){v[5].y, -v[5].x};         // w8^2 = -i
    v[7] = cmulw(v[7], (v2f){-C2, C2});    // w8^3
#pragma unroll
    for (int k0 = 0; k0 < 4; ++k0) {
        v2f a = v[2 * k0], b = v[2 * k0 + 1];
        v[2 * k0]     = a + b;
        v[2 * k0 + 1] = a - b;
    }
}

// apply twiddles w^r (r=1..7) for base angle th (revolutions) via recurrence
__device__ __forceinline__ void twiddle7(v2f* v, float th) {
    v2f w1 = (v2f){cosr(th), sinr(th)};
    v2f w = w1;
    v[1] = cmulw(v[1], w);
#pragma unroll
    for (int r = 2; r < 8; ++r) {
        w = cmul(w, w1);
        v[r] = cmulw(v[r], w);
    }
}

// One block per ROW PAIR: z = g0*x0 + i*g1*x1, 4096-pt FFT (radix-8 x 4,
// 512 threads, packed-f32), hierarchical wave-parallel top-8, sparse inverse.
__global__ __launch_bounds__(THREADS, 8)
void fft2_topk_k(const float* __restrict__ x, const float* __restrict__ te,
                 const float* __restrict__ W, const float* __restrict__ bias,
                 float* __restrict__ out) {
    __shared__ v2f zb[LL];                  // 32 KB
    __shared__ float wv[8];
    __shared__ float candV[2][33];
    __shared__ int   candB[2][33];
    __shared__ v2f  selAB[2][KK];           // (A, B)
    __shared__ v2f  selST[2][KK];           // rotator step (cos, sin)
    __shared__ int  selF[2][KK];

    int t = threadIdx.x;
    int pair = blockIdx.x;
    int b = pair >> 6;
    int c0 = (pair & 63) << 1;
    int row0 = (b << 7) + c0;

    // modulation dots: threads<256 -> row0, >=256 -> row1
    {
        int mh = t >> 8, tt = t & 255;
        const float* tp = te + b * 512;
        const float* wp = W + (c0 + mh) * 512;
        float ps = tp[tt] * wp[tt] + tp[tt + 256] * wp[tt + 256];
#pragma unroll
        for (int off = 32; off; off >>= 1) ps += __shfl_down(ps, off);
        if ((t & 63) == 0) wv[t >> 6] = ps;
    }

    const float* xp0 = x + (size_t)row0 * LL;
    const float* xp1 = xp0 + LL;
    v2f v[8];
#pragma unroll
    for (int r = 0; r < 8; ++r) { v[r].x = xp0[t + 512 * r]; v[r].y = xp1[t + 512 * r]; }
    __syncthreads();
    float g0 = 1.0f + tanhf(wv[0] + wv[1] + wv[2] + wv[3] + bias[c0]);
    float g1 = 1.0f + tanhf(wv[4] + wv[5] + wv[6] + wv[7] + bias[c0 + 1]);
    {
        v2f g = (v2f){g0, g1};
#pragma unroll
        for (int r = 0; r < 8; ++r) v[r] *= g;
    }

    // ---- pass 0 (Ns=1): no twiddle ----
    dft8(v);
#pragma unroll
    for (int r = 0; r < 8; ++r) zb[SW(t * 8 + r)] = v[PERM8(r)];
    __syncthreads();

    // ---- pass 1 (Ns=8) ----
#pragma unroll
    for (int r = 0; r < 8; ++r) v[r] = zb[SW(t + 512 * r)];
    twiddle7(v, (float)(t & 7) * (1.0f / 64.0f));
    dft8(v);
    __syncthreads();
    {
        int base = ((t >> 3) << 6) + (t & 7);
#pragma unroll
        for (int r = 0; r < 8; ++r) zb[SW(base + 8 * r)] = v[PERM8(r)];
    }
    __syncthreads();

    // ---- pass 2 (Ns=64) ----
#pragma unroll
    for (int r = 0; r < 8; ++r) v[r] = zb[SW(t + 512 * r)];
    twiddle7(v, (float)(t & 63) * (1.0f / 512.0f));
    dft8(v);
    __syncthreads();
    {
        int base = ((t >> 6) << 9) + (t & 63);
#pragma unroll
        for (int r = 0; r < 8; ++r) zb[SW(base + 64 * r)] = v[PERM8(r)];
    }
    __syncthreads();

    // ---- pass 3 (Ns=512): natural-order Z ----
#pragma unroll
    for (int r = 0; r < 8; ++r) v[r] = zb[SW(t + 512 * r)];
    twiddle7(v, (float)t * (1.0f / 4096.0f));
    dft8(v);
    __syncthreads();
#pragma unroll
    for (int r = 0; r < 8; ++r) zb[SW(t + 512 * r)] = v[PERM8(r)];
    __syncthreads();

    int wid = t >> 6, lane = t & 63;
    int half = wid >> 2, w2 = wid & 3;

    // ---- per-wave local top-8 over a 512-bin slice (8 bins/lane) ----
    // amp uses 2X (untangle sans 0.5): ranking-invariant. Bin 2048 handled
    // at merge. X1=(Z[k]+conj(Z[-k])), X2=-i(Z[k]-conj(Z[-k])).
    {
        int kbase = (w2 << 9) + lane;
        float amp[8];
#pragma unroll
        for (int m = 0; m < 8; ++m) {
            int k = kbase + (m << 6);
            v2f z = zb[SW(k)];
            v2f y = zb[SW((4096 - k) & 4095)];
            float Xr, Xi;
            if (half == 0) { Xr = z.x + y.x; Xi = z.y - y.y; }
            else           { Xr = z.y + y.y; Xi = y.x - z.x; }
            amp[m] = Xr * Xr + Xi * Xi;
        }
        for (int it = 0; it < KK; ++it) {
            float bv = -1.f; int bm = 0;
#pragma unroll
            for (int m = 0; m < 8; ++m)             // ascending m: lower bin on tie
                if (amp[m] > bv) { bv = amp[m]; bm = m; }
            int bb = kbase + (bm << 6);
#pragma unroll
            for (int off = 32; off; off >>= 1) {
                float ov = __shfl_down(bv, off);
                int   ob = __shfl_down(bb, off);
                if (ov > bv || (ov == bv && ob < bb)) { bv = ov; bb = ob; }
            }
            int wb = __shfl(bb, 0);                 // winner bin broadcast
            if ((wb & 63) == lane) {                // owner removes it
                int sm = (wb >> 6) & 7;
#pragma unroll
                for (int m = 0; m < 8; ++m)
                    if (m == sm) amp[m] = -1.f;
            }
            if (lane == 0) {
                candV[half][(w2 << 3) + it] = bv;
                candB[half][(w2 << 3) + it] = bb;
            }
        }
    }
    __syncthreads();

    // ---- merge 33 candidates per row: wave 0 -> row0, wave 4 -> row1 ----
    if (w2 == 0) {
        float cv; int cb;
        if (lane < 32)      { cv = candV[half][lane]; cb = candB[half][lane]; }
        else if (lane == 32) {
            v2f z = zb[SW(2048)];                   // self-mirror bin
            float Xr = 2.0f * (half ? z.y : z.x);   // matches 2X scaling
            cv = Xr * Xr; cb = 2048;
        } else              { cv = -1.f; cb = 1 << 30; }
        for (int it = 0; it < KK; ++it) {
            float bv = cv; int bb = cb;
#pragma unroll
            for (int off = 32; off; off >>= 1) {
                float ov = __shfl_down(bv, off);
                int   ob = __shfl_down(bb, off);
                if (ov > bv || (ov == bv && ob < bb)) { bv = ov; bb = ob; }
            }
            int wb = __shfl(bb, 0);
            if (cb == wb) cv = -1.f;                // remove winner
            if (lane == 0) {                        // record exact X(wb)
                v2f z = zb[SW(wb)];
                v2f y = zb[SW((4096 - wb) & 4095)];
                v2f X;
                if (half == 0) X = (v2f){0.5f * (z.x + y.x), 0.5f * (z.y - y.y)};
                else           X = (v2f){0.5f * (z.y + y.y), 0.5f * (y.x - z.x)};
                bool edge = (wb == 0) || (wb == 2048);
                float wgt = edge ? 1.f : 2.f;
                selF[half][it] = wb;
                selAB[half][it] = (v2f){wgt * (1.0f / 4096.0f) * X.x,
                                        edge ? 0.f : wgt * (1.0f / 4096.0f) * X.y};
                float a = (float)((wb & 15) << 8) * (1.0f / 4096.0f);
                selST[half][it] = (v2f){cosr(a), sinr(a)};
            }
        }
    }
    __syncthreads();

    // ---- sparse inverse: threads<256 -> row0, >=256 -> row1 ----
    // w_k[n] = (A+iB) e^{2pi i f n/L}; out[n]=sum Re(w_k); out[n+2048] via
    // (-1)^f. 8 rotator steps of 256 samples each.
    {
        int mh = t >> 8, u = t & 255;
        v2f w[KK], st[KK]; float sg[KK];
        const float i4096 = 1.0f / 4096.0f;
#pragma unroll
        for (int k = 0; k < KK; ++k) {
            int f = selF[mh][k];
            int m0 = (f * u) & 4095;
            float a0 = (float)m0 * i4096;
            w[k] = cmul(selAB[mh][k], (v2f){cosr(a0), sinr(a0)});
            st[k] = selST[mh][k];
            sg[k] = (f & 1) ? -1.f : 1.f;
        }
        float* op = out + (size_t)(row0 + mh) * LL;
#pragma unroll 1
        for (int q = 0; q < 8; ++q) {
            float acc = 0.f, acd = 0.f;
#pragma unroll
            for (int k = 0; k < KK; ++k) {
                acc += w[k].x;
                acd = fmaf(sg[k], w[k].x, acd);
                w[k] = cmul(w[k], st[k]);
            }
            op[u + (q << 8)] = acc;
            op[u + (q << 8) + 2048] = acd;
        }
    }
}

extern "C" void kernel_launch(void* const* d_in, const int* in_sizes, int n_in,
                              void* d_out, int out_size, void* d_ws, size_t ws_size,
                              hipStream_t stream) {
    const float* x    = (const float*)d_in[0];
    const float* te   = (const float*)d_in[1];
    const float* W    = (const float*)d_in[2];
    const float* bias = (const float*)d_in[3];
    float* out = (float*)d_out;
    fft2_topk_k<<<2048, THREADS, 0, stream>>>(x, te, W, bias, out);
}

// Round 8
// 55.368 us; speedup vs baseline: 1.2129x; 1.2129x over previous
//
#include <hip/hip_runtime.h>

#define LL 4096
#define THREADS 512
#define KK 8

typedef float v2f __attribute__((ext_vector_type(2)));

// Pad-1-per-8 layout: elem i lives at i + (i>>3). Verified conflict-free
// (uniform 4 touches/bank for b64) for ALL patterns in this kernel, and
// every FFT pass's 8 accesses become base + constant -> ds offset immediates.
#define PD(i) ((i) + ((i) >> 3))
// dft8: X[k0+4*k1] sits in slot 2*k0+k1 -> slot holding X[r]:
#define PERM8(r) ((((r) & 3) << 1) | ((r) >> 2))

// HW trig, input in REVOLUTIONS: sinr(x)=sin(2*pi*x). All args are exact
// m/2^k in [0,1), so no range-reduction error.
__device__ __forceinline__ float sinr(float x) {
    float r; asm("v_sin_f32 %0, %1" : "=v"(r) : "v"(x)); return r;
}
__device__ __forceinline__ float cosr(float x) {
    float r; asm("v_cos_f32 %0, %1" : "=v"(r) : "v"(x)); return r;
}

// twiddle apply: multiply z=(zr,zi) by (c - i*s), w=(c,s)
__device__ __forceinline__ v2f cmulw(v2f z, v2f w) {
    v2f zs = __builtin_shufflevector(z, z, 1, 0);      // (zi, zr)
    v2f res = z * (v2f){w.x, w.x};
    res += zs * (v2f){w.y, -w.y};
    return res;
}
// standard complex multiply (a.x+i a.y)(b.x+i b.y)
__device__ __forceinline__ v2f cmul(v2f a, v2f b) {
    v2f as = __builtin_shufflevector(a, a, 1, 0);
    v2f res = a * (v2f){b.x, b.x};
    res += as * (v2f){-b.y, b.y};
    return res;
}

// forward 4-point DFT (w4 = -i), in place, complex-packed
__device__ __forceinline__ void dft4(v2f& a, v2f& b, v2f& c, v2f& d) {
    v2f t0 = a + c, t1 = a - c, t2 = b + d, t3 = b - d;
    a = t0 + t2; c = t0 - t2;
    v2f t3n = (v2f){t3.y, -t3.x};   // -i * t3
    b = t1 + t3n; d = t1 - t3n;
}

// forward 8-point DFT; output permuted per PERM8
__device__ __forceinline__ void dft8(v2f* v) {
    dft4(v[0], v[2], v[4], v[6]);
    dft4(v[1], v[3], v[5], v[7]);
    const float C2 = 0.70710678118654752f;
    v[3] = cmulw(v[3], (v2f){C2, C2});     // w8^1
    v[5] = (v2f){v[5].y, -v[5].x};         // w8^2 = -i
    v[7] = cmulw(v[7], (v2f){-C2, C2});    // w8^3
#pragma unroll
    for (int k0 = 0; k0 < 4; ++k0) {
        v2f a = v[2 * k0], b = v[2 * k0 + 1];
        v[2 * k0]     = a + b;
        v[2 * k0 + 1] = a - b;
    }
}

// apply twiddles w^r (r=1..7) for base angle th (revolutions) via recurrence
__device__ __forceinline__ void twiddle7(v2f* v, float th) {
    v2f w1 = (v2f){cosr(th), sinr(th)};
    v2f w = w1;
    v[1] = cmulw(v[1], w);
#pragma unroll
    for (int r = 2; r < 8; ++r) {
        w = cmul(w, w1);
        v[r] = cmulw(v[r], w);
    }
}

// One block per ROW PAIR: z = g0*x0 + i*g1*x1, 4096-pt FFT (radix-8 x 4,
// padded LDS layout, immediate-offset DS addressing), 4-wave top-8 with
// merge-path combine, sparse inverse via 8 register rotators.
__global__ __launch_bounds__(THREADS, 8)
void fft2_topk_k(const float* __restrict__ x, const float* __restrict__ te,
                 const float* __restrict__ W, const float* __restrict__ bias,
                 float* __restrict__ out) {
    __shared__ v2f zb[4608];               // 36 KB padded
    __shared__ float wv[8];
    __shared__ float candV[2][16];         // [row][half*8+i], each half sorted desc
    __shared__ int   candB[2][16];
    __shared__ v2f  selAB[2][KK];          // (A, B)
    __shared__ v2f  selST[2][KK];          // rotator step (cos, sin)
    __shared__ int  selF[2][KK];

    int t = threadIdx.x;
    int pair = blockIdx.x;
    int b = pair >> 6;
    int c0 = (pair & 63) << 1;
    int row0 = (b << 7) + c0;

    // modulation dots: threads<256 -> row0, >=256 -> row1
    {
        int mh = t >> 8, tt = t & 255;
        const float* tp = te + b * 512;
        const float* wp = W + (c0 + mh) * 512;
        float ps = tp[tt] * wp[tt] + tp[tt + 256] * wp[tt + 256];
#pragma unroll
        for (int off = 32; off; off >>= 1) ps += __shfl_down(ps, off);
        if ((t & 63) == 0) wv[t >> 6] = ps;
    }

    const float* xp0 = x + (size_t)row0 * LL;
    const float* xp1 = xp0 + LL;
    v2f v[8];
#pragma unroll
    for (int r = 0; r < 8; ++r) { v[r].x = xp0[t + 512 * r]; v[r].y = xp1[t + 512 * r]; }
    __syncthreads();
    float g0 = 1.0f + tanhf(wv[0] + wv[1] + wv[2] + wv[3] + bias[c0]);
    float g1 = 1.0f + tanhf(wv[4] + wv[5] + wv[6] + wv[7] + bias[c0 + 1]);
    {
        v2f g = (v2f){g0, g1};
#pragma unroll
        for (int r = 0; r < 8; ++r) v[r] *= g;
    }

    // ---- pass 0 (Ns=1): write elem 8t+r -> PD = 9t + r ----
    dft8(v);
    {
        int wb = 9 * t;
#pragma unroll
        for (int r = 0; r < 8; ++r) zb[wb + r] = v[PERM8(r)];
    }
    __syncthreads();

    int rb = t + (t >> 3);                 // PD(t + 512r) = rb + 576r

    // ---- pass 1 (Ns=8): write elem 64(t>>3)+(t&7)+8r -> PD = wb + 9r ----
#pragma unroll
    for (int r = 0; r < 8; ++r) v[r] = zb[rb + 576 * r];
    twiddle7(v, (float)(t & 7) * (1.0f / 64.0f));
    dft8(v);
    __syncthreads();
    {
        int wb = 72 * (t >> 3) + (t & 7);
#pragma unroll
        for (int r = 0; r < 8; ++r) zb[wb + 9 * r] = v[PERM8(r)];
    }
    __syncthreads();

    // ---- pass 2 (Ns=64): write elem 512(t>>6)+(t&63)+64r -> PD = wb + 72r ----
#pragma unroll
    for (int r = 0; r < 8; ++r) v[r] = zb[rb + 576 * r];
    twiddle7(v, (float)(t & 63) * (1.0f / 512.0f));
    dft8(v);
    __syncthreads();
    {
        int l6 = t & 63;
        int wb = 576 * (t >> 6) + l6 + (l6 >> 3);
#pragma unroll
        for (int r = 0; r < 8; ++r) zb[wb + 72 * r] = v[PERM8(r)];
    }
    __syncthreads();

    // ---- pass 3 (Ns=512): per-thread read/write sets identical -> in-place,
    // no extra barrier between read and write ----
#pragma unroll
    for (int r = 0; r < 8; ++r) v[r] = zb[rb + 576 * r];
    twiddle7(v, (float)t * (1.0f / 4096.0f));
    dft8(v);
#pragma unroll
    for (int r = 0; r < 8; ++r) zb[rb + 576 * r] = v[PERM8(r)];
    __syncthreads();

    int wid = t >> 6, lane = t & 63;

    // ---- top-8: 4 waves (2/row), 16 bins/lane, running local max, no syncs.
    // amp uses 2X (untangle sans 0.5) — ranking-invariant.
    if (wid < 4) {
        int row = wid >> 1, hf = wid & 1;
        int kb = (hf << 10) + lane;        // bins kb + 64m, m=0..15
        float amp[16];
        float lv = -1.f; int lm = 0;
#pragma unroll
        for (int m = 0; m < 16; ++m) {
            int k = kb + (m << 6);
            v2f z = zb[PD(k)];
            v2f y = zb[PD((4096 - k) & 4095)];
            float Xr = row ? (z.y + y.y) : (z.x + y.x);
            float Xi = row ? (y.x - z.x) : (z.y - y.y);
            float a = Xr * Xr + Xi * Xi;
            amp[m] = a;
            if (a > lv) { lv = a; lm = m; }   // ascending m => lower bin on tie
        }
        for (int it = 0; it < KK; ++it) {
            float bv = lv; int bb = kb + (lm << 6);
#pragma unroll
            for (int off = 32; off; off >>= 1) {
                float ov = __shfl_down(bv, off);
                int   ob = __shfl_down(bb, off);
                if (ov > bv || (ov == bv && ob < bb)) { bv = ov; bb = ob; }
            }
            if (lane == 0) { candV[row][(hf << 3) + it] = bv; candB[row][(hf << 3) + it] = bb; }
            int wbin = __shfl(bb, 0);
            int rel = wbin - (hf << 10);
            if ((rel & 63) == lane) {          // owner removes + rescans (masked)
                int m0 = rel >> 6;
                lv = -1.f; lm = 0;
#pragma unroll
                for (int m = 0; m < 16; ++m) {
                    float a = (m == m0) ? -1.f : amp[m];
                    amp[m] = a;
                    if (a > lv) { lv = a; lm = m; }
                }
            }
        }
    }
    __syncthreads();

    // ---- merge-path combine: wave0 -> row0, wave1 -> row1; 17 candidates
    // (two sorted 8-lists + bin 2048). rank = in-list index + cross beats.
    if (wid < 2 && lane < 17) {
        int row = wid;
        v2f z2 = zb[PD(2048)];
        float xn = 2.f * (row ? z2.y : z2.x);   // matches 2X amp scaling
        float a2048 = xn * xn;
        float myv; int myb, rank;
        if (lane < 16) {
            myv = candV[row][lane]; myb = candB[row][lane];
            rank = lane & 7;
            int ob = (lane < 8) ? 8 : 0;        // compare vs the other list
#pragma unroll
            for (int j = 0; j < 8; ++j) {
                float ov = candV[row][ob + j]; int obn = candB[row][ob + j];
                if (ov > myv || (ov == myv && obn < myb)) rank++;
            }
            if (a2048 > myv) rank++;            // 2048 is highest bin: strict >
        } else {
            myv = a2048; myb = 2048; rank = 0;
#pragma unroll
            for (int j = 0; j < 16; ++j)
                if (candV[row][j] >= myv) rank++;   // ties beat bin 2048
        }
        if (rank < KK) {                        // top-8 member: record
            v2f z = zb[PD(myb)];
            v2f y = zb[PD((4096 - myb) & 4095)];
            v2f X;
            if (row == 0) X = (v2f){0.5f * (z.x + y.x), 0.5f * (z.y - y.y)};
            else          X = (v2f){0.5f * (z.y + y.y), 0.5f * (y.x - z.x)};
            bool edge = (myb == 0) || (myb == 2048);
            float wgt = edge ? 1.f : 2.f;
            selF[row][rank] = myb;
            selAB[row][rank] = (v2f){wgt * (1.0f / 4096.0f) * X.x,
                                     edge ? 0.f : wgt * (1.0f / 4096.0f) * X.y};
            float a = (float)((myb & 15) << 8) * (1.0f / 4096.0f);
            selST[row][rank] = (v2f){cosr(a), sinr(a)};
        }
    }
    __syncthreads();

    // ---- sparse inverse: threads<256 -> row0, >=256 -> row1 ----
    // w_k[n] = (A+iB) e^{2pi i f n/L}; out[n]=sum Re(w_k); out[n+2048] via
    // (-1)^f. 8 rotator steps of 256 samples each.
    {
        int mh = t >> 8, u = t & 255;
        v2f w[KK], st[KK]; float sg[KK];
        const float i4096 = 1.0f / 4096.0f;
#pragma unroll
        for (int k = 0; k < KK; ++k) {
            int f = selF[mh][k];
            int m0 = (f * u) & 4095;
            float a0 = (float)m0 * i4096;
            w[k] = cmul(selAB[mh][k], (v2f){cosr(a0), sinr(a0)});
            st[k] = selST[mh][k];
            sg[k] = (f & 1) ? -1.f : 1.f;
        }
        float* op = out + (size_t)(row0 + mh) * LL;
#pragma unroll 1
        for (int q = 0; q < 8; ++q) {
            float acc = 0.f, acd = 0.f;
#pragma unroll
            for (int k = 0; k < KK; ++k) {
                acc += w[k].x;
                acd = fmaf(sg[k], w[k].x, acd);
                w[k] = cmul(w[k], st[k]);
            }
            op[u + (q << 8)] = acc;
            op[u + (q << 8) + 2048] = acd;
        }
    }
}

extern "C" void kernel_launch(void* const* d_in, const int* in_sizes, int n_in,
                              void* d_out, int out_size, void* d_ws, size_t ws_size,
                              hipStream_t stream) {
    const float* x    = (const float*)d_in[0];
    const float* te   = (const float*)d_in[1];
    const float* W    = (const float*)d_in[2];
    const float* bias = (const float*)d_in[3];
    float* out = (float*)d_out;
    fft2_topk_k<<<2048, THREADS, 0, stream>>>(x, te, W, bias, out);
}

// Round 9
// 53.074 us; speedup vs baseline: 1.2653x; 1.0432x over previous
//
#include <hip/hip_runtime.h>

#define LL 4096
#define THREADS 512
#define KK 8

typedef float v2f __attribute__((ext_vector_type(2)));

// Pad-1-per-16 layout: elem i lives at i + (i>>4). Verified: every access
// pattern in this kernel (all pass writes, stride-512 reads, top-k direct +
// mirror reads) is uniform 4 lanes per bank-pair for b64 = conflict-free
// minimum, and every FFT pass access folds to base + compile-time offset.
#define PD(i) ((i) + ((i) >> 4))
// dft8: X[k0+4*k1] sits in slot 2*k0+k1 -> slot holding X[r]:
#define PERM8(r) ((((r) & 3) << 1) | ((r) >> 2))

// HW trig, input in REVOLUTIONS: sinr(x)=sin(2*pi*x). All args are exact
// m/2^k in [0,1), so no range-reduction error.
__device__ __forceinline__ float sinr(float x) {
    float r; asm("v_sin_f32 %0, %1" : "=v"(r) : "v"(x)); return r;
}
__device__ __forceinline__ float cosr(float x) {
    float r; asm("v_cos_f32 %0, %1" : "=v"(r) : "v"(x)); return r;
}

// twiddle apply: multiply z=(zr,zi) by (c - i*s), w=(c,s)
__device__ __forceinline__ v2f cmulw(v2f z, v2f w) {
    v2f zs = __builtin_shufflevector(z, z, 1, 0);      // (zi, zr)
    v2f res = z * (v2f){w.x, w.x};
    res += zs * (v2f){w.y, -w.y};
    return res;
}
// standard complex multiply (a.x+i a.y)(b.x+i b.y)
__device__ __forceinline__ v2f cmul(v2f a, v2f b) {
    v2f as = __builtin_shufflevector(a, a, 1, 0);
    v2f res = a * (v2f){b.x, b.x};
    res += as * (v2f){-b.y, b.y};
    return res;
}

// forward 4-point DFT (w4 = -i), in place, complex-packed
__device__ __forceinline__ void dft4(v2f& a, v2f& b, v2f& c, v2f& d) {
    v2f t0 = a + c, t1 = a - c, t2 = b + d, t3 = b - d;
    a = t0 + t2; c = t0 - t2;
    v2f t3n = (v2f){t3.y, -t3.x};   // -i * t3
    b = t1 + t3n; d = t1 - t3n;
}

// forward 8-point DFT; output permuted per PERM8
__device__ __forceinline__ void dft8(v2f* v) {
    dft4(v[0], v[2], v[4], v[6]);
    dft4(v[1], v[3], v[5], v[7]);
    const float C2 = 0.70710678118654752f;
    v[3] = cmulw(v[3], (v2f){C2, C2});     // w8^1
    v[5] = (v2f){v[5].y, -v[5].x};         // w8^2 = -i
    v[7] = cmulw(v[7], (v2f){-C2, C2});    // w8^3
#pragma unroll
    for (int k0 = 0; k0 < 4; ++k0) {
        v2f a = v[2 * k0], b = v[2 * k0 + 1];
        v[2 * k0]     = a + b;
        v[2 * k0 + 1] = a - b;
    }
}

// apply twiddles w^r (r=1..7), tree-structured powers (dep depth 3, not 7)
__device__ __forceinline__ void twiddle7(v2f* v, float th) {
    v2f w1 = (v2f){cosr(th), sinr(th)};
    v2f w2 = cmul(w1, w1);
    v2f w3 = cmul(w2, w1);
    v2f w4 = cmul(w2, w2);
    v2f w5 = cmul(w3, w2);
    v2f w6 = cmul(w3, w3);
    v2f w7 = cmul(w4, w3);
    v[1] = cmulw(v[1], w1);
    v[2] = cmulw(v[2], w2);
    v[3] = cmulw(v[3], w3);
    v[4] = cmulw(v[4], w4);
    v[5] = cmulw(v[5], w5);
    v[6] = cmulw(v[6], w6);
    v[7] = cmulw(v[7], w7);
}

// One block per ROW PAIR: z = g0*x0 + i*g1*x1, 4096-pt FFT (radix-8 x 4,
// padded LDS, immediate-offset DS), 4-wave top-8 + merge-path combine,
// sparse inverse via packed Chebyshev recurrence.
__global__ __launch_bounds__(THREADS, 8)
void fft2_topk_k(const float* __restrict__ x, const float* __restrict__ te,
                 const float* __restrict__ W, const float* __restrict__ bias,
                 float* __restrict__ out) {
    __shared__ v2f zb[4352];               // PD(4095)=4350; 34.8 KB
    __shared__ float wv[8];
    __shared__ float candV[2][16];         // [row][half*8+i], halves sorted desc
    __shared__ int   candB[2][16];
    __shared__ v2f  selAB[2][KK];          // (A, B)
    __shared__ int  selF[2][KK];

    int t = threadIdx.x;
    int pair = blockIdx.x;
    int b = pair >> 6;
    int c0 = (pair & 63) << 1;
    int row0 = (b << 7) + c0;

    // modulation dots: threads<256 -> row0, >=256 -> row1
    {
        int mh = t >> 8, tt = t & 255;
        const float* tp = te + b * 512;
        const float* wp = W + (c0 + mh) * 512;
        float ps = tp[tt] * wp[tt] + tp[tt + 256] * wp[tt + 256];
#pragma unroll
        for (int off = 32; off; off >>= 1) ps += __shfl_down(ps, off);
        if ((t & 63) == 0) wv[t >> 6] = ps;
    }

    const float* xp0 = x + (size_t)row0 * LL;
    const float* xp1 = xp0 + LL;
    v2f v[8];
#pragma unroll
    for (int r = 0; r < 8; ++r) { v[r].x = xp0[t + 512 * r]; v[r].y = xp1[t + 512 * r]; }
    __syncthreads();
    float g0 = 1.0f + tanhf(wv[0] + wv[1] + wv[2] + wv[3] + bias[c0]);
    float g1 = 1.0f + tanhf(wv[4] + wv[5] + wv[6] + wv[7] + bias[c0 + 1]);
    {
        v2f g = (v2f){g0, g1};
#pragma unroll
        for (int r = 0; r < 8; ++r) v[r] *= g;
    }

    // ---- pass 0 (Ns=1): elem 8t+r -> PD = 8t + (t>>1) + r ----
    dft8(v);
    {
        int wb = 8 * t + (t >> 1);
#pragma unroll
        for (int r = 0; r < 8; ++r) zb[wb + r] = v[PERM8(r)];
    }
    __syncthreads();

    int rb = t + (t >> 4);                 // PD(t + 512r) = rb + 544r

    // ---- pass 1 (Ns=8): elem 64a+b+8r (a=t>>3,b=t&7); even r: B0+17s,
    // odd r: B1+17s ----
#pragma unroll
    for (int r = 0; r < 8; ++r) v[r] = zb[rb + 544 * r];
    twiddle7(v, (float)(t & 7) * (1.0f / 64.0f));
    dft8(v);
    __syncthreads();
    {
        int wb = 64 * (t >> 3) + (t & 7);
        int B0 = wb + (wb >> 4);
        int B1 = (wb + 8) + ((wb + 8) >> 4);
#pragma unroll
        for (int s = 0; s < 4; ++s) {
            zb[B0 + 17 * s] = v[PERM8(2 * s)];
            zb[B1 + 17 * s] = v[PERM8(2 * s + 1)];
        }
    }
    __syncthreads();

    // ---- pass 2 (Ns=64): elem 512(t>>6)+(t&63)+64r -> PD = B2 + 68r ----
#pragma unroll
    for (int r = 0; r < 8; ++r) v[r] = zb[rb + 544 * r];
    twiddle7(v, (float)(t & 63) * (1.0f / 512.0f));
    dft8(v);
    __syncthreads();
    {
        int wb = 512 * (t >> 6) + (t & 63);
        int B2 = wb + (wb >> 4);
#pragma unroll
        for (int r = 0; r < 8; ++r) zb[B2 + 68 * r] = v[PERM8(r)];
    }
    __syncthreads();

    // ---- pass 3 (Ns=512): per-thread read/write sets identical -> in-place ----
#pragma unroll
    for (int r = 0; r < 8; ++r) v[r] = zb[rb + 544 * r];
    twiddle7(v, (float)t * (1.0f / 4096.0f));
    dft8(v);
#pragma unroll
    for (int r = 0; r < 8; ++r) zb[rb + 544 * r] = v[PERM8(r)];
    __syncthreads();

    int wid = t >> 6, lane = t & 63;

    // ---- top-8: 4 waves (2/row), 16 bins/lane, running local max, no syncs.
    // amp uses 2X (untangle sans 0.5) — ranking-invariant.
    if (wid < 4) {
        int row = wid >> 1, hf = wid & 1;
        int kb = (hf << 10) + lane;        // bins kb + 64m, m=0..15
        float amp[16];
        float lv = -1.f; int lm = 0;
#pragma unroll
        for (int m = 0; m < 16; ++m) {
            int k = kb + (m << 6);
            v2f z = zb[PD(k)];
            int kq = (4096 - k) & 4095;
            v2f y = zb[PD(kq)];
            float Xr = row ? (z.y + y.y) : (z.x + y.x);
            float Xi = row ? (y.x - z.x) : (z.y - y.y);
            float a = Xr * Xr + Xi * Xi;
            amp[m] = a;
            if (a > lv) { lv = a; lm = m; }   // ascending m => lower bin on tie
        }
        for (int it = 0; it < KK; ++it) {
            float bv = lv; int bb = kb + (lm << 6);
#pragma unroll
            for (int off = 32; off; off >>= 1) {
                float ov = __shfl_down(bv, off);
                int   ob = __shfl_down(bb, off);
                if (ov > bv || (ov == bv && ob < bb)) { bv = ov; bb = ob; }
            }
            if (lane == 0) { candV[row][(hf << 3) + it] = bv; candB[row][(hf << 3) + it] = bb; }
            int wbin = __shfl(bb, 0);
            int rel = wbin - (hf << 10);
            if ((rel & 63) == lane) {          // owner removes + rescans (masked)
                int m0 = rel >> 6;
                lv = -1.f; lm = 0;
#pragma unroll
                for (int m = 0; m < 16; ++m) {
                    float a = (m == m0) ? -1.f : amp[m];
                    amp[m] = a;
                    if (a > lv) { lv = a; lm = m; }
                }
            }
        }
    }
    __syncthreads();

    // ---- merge-path combine: wave0 -> row0, wave1 -> row1; 17 candidates
    // (two sorted 8-lists + bin 2048). rank = in-list index + cross beats.
    if (wid < 2 && lane < 17) {
        int row = wid;
        v2f z2 = zb[PD(2048)];
        float xn = 2.f * (row ? z2.y : z2.x);   // matches 2X amp scaling
        float a2048 = xn * xn;
        float myv; int myb, rank;
        if (lane < 16) {
            myv = candV[row][lane]; myb = candB[row][lane];
            rank = lane & 7;
            int ob = (lane < 8) ? 8 : 0;        // compare vs the other list
#pragma unroll
            for (int j = 0; j < 8; ++j) {
                float ov = candV[row][ob + j]; int obn = candB[row][ob + j];
                if (ov > myv || (ov == myv && obn < myb)) rank++;
            }
            if (a2048 > myv) rank++;            // 2048 is highest bin: strict >
        } else {
            myv = a2048; myb = 2048; rank = 0;
#pragma unroll
            for (int j = 0; j < 16; ++j)
                if (candV[row][j] >= myv) rank++;   // ties beat bin 2048
        }
        if (rank < KK) {                        // top-8 member: record
            v2f z = zb[PD(myb)];
            int mq = (4096 - myb) & 4095;
            v2f y = zb[PD(mq)];
            v2f X;
            if (row == 0) X = (v2f){0.5f * (z.x + y.x), 0.5f * (z.y - y.y)};
            else          X = (v2f){0.5f * (z.y + y.y), 0.5f * (y.x - z.x)};
            bool edge = (myb == 0) || (myb == 2048);
            float wgt = edge ? 1.f : 2.f;
            selF[row][rank] = myb;
            selAB[row][rank] = (v2f){wgt * (1.0f / 4096.0f) * X.x,
                                     edge ? 0.f : wgt * (1.0f / 4096.0f) * X.y};
        }
    }
    __syncthreads();

    // ---- sparse inverse via packed Chebyshev recurrence ----
    // r_k(q) = Re[(A+iB)e^{i*2pi*f*(u+256q)/L}] satisfies
    // r(q+1) = 2cos(2pi*f*256/L)*r(q) - r(q-1). Two freqs per v2f.
    // out[u+256q] = sum_k r_k(q); out[u+256q+2048] = sum_k (-1)^{f_k} r_k(q).
    {
        int mh = t >> 8, u = t & 255;
        const float i4096 = 1.0f / 4096.0f;
        v2f rc[4], rp[4], tcv[4], sgv[4];
#pragma unroll
        for (int j = 0; j < 4; ++j) {
            int f0 = selF[mh][2 * j], f1 = selF[mh][2 * j + 1];
            v2f A0 = selAB[mh][2 * j], A1 = selAB[mh][2 * j + 1];
            int m0a = (f0 * u) & 4095, m0b = (f1 * u) & 4095;
            float c0a = cosr((float)m0a * i4096), s0a = sinr((float)m0a * i4096);
            float c0b = cosr((float)m0b * i4096), s0b = sinr((float)m0b * i4096);
            float r0a = A0.x * c0a - A0.y * s0a;    // Re w(u)
            float i0a = A0.x * s0a + A0.y * c0a;    // Im w(u)
            float r0b = A1.x * c0b - A1.y * s0b;
            float i0b = A1.x * s0b + A1.y * c0b;
            float da = (float)((f0 & 15) << 8) * i4096;   // step angle (rev)
            float db = (float)((f1 & 15) << 8) * i4096;
            float cda = cosr(da), sda = sinr(da);
            float cdb = cosr(db), sdb = sinr(db);
            rc[j] = (v2f){r0a, r0b};
            // r(-1) = Re[w(u) e^{-i*step}] = Re*cos + Im*sin
            rp[j] = (v2f){r0a * cda + i0a * sda, r0b * cdb + i0b * sdb};
            tcv[j] = (v2f){cda + cda, cdb + cdb};
            sgv[j] = (v2f){(f0 & 1) ? -1.f : 1.f, (f1 & 1) ? -1.f : 1.f};
        }
        float* op = out + (size_t)(row0 + mh) * LL;
#pragma unroll
        for (int q = 0; q < 8; ++q) {
            v2f accv = (rc[0] + rc[1]) + (rc[2] + rc[3]);
            v2f acdv = rc[0] * sgv[0] + rc[1] * sgv[1]
                     + rc[2] * sgv[2] + rc[3] * sgv[3];
            op[u + (q << 8)] = accv.x + accv.y;
            op[u + (q << 8) + 2048] = acdv.x + acdv.y;
#pragma unroll
            for (int j = 0; j < 4; ++j) {
                v2f rn = tcv[j] * rc[j] - rp[j];
                rp[j] = rc[j];
                rc[j] = rn;
            }
        }
    }
}

extern "C" void kernel_launch(void* const* d_in, const int* in_sizes, int n_in,
                              void* d_out, int out_size, void* d_ws, size_t ws_size,
                              hipStream_t stream) {
    const float* x    = (const float*)d_in[0];
    const float* te   = (const float*)d_in[1];
    const float* W    = (const float*)d_in[2];
    const float* bias = (const float*)d_in[3];
    float* out = (float*)d_out;
    fft2_topk_k<<<2048, THREADS, 0, stream>>>(x, te, W, bias, out);
}